// Round 8
// baseline (291.100 us; speedup 1.0000x reference)
//
#include <hip/hip_runtime.h>
#include <math.h>

#define NN 100000
#define NE 1600000
#define D 128
#define BN_EPS 1e-5f
#define NCHUNK 391   // ceil(NN/256)
#define GSZ 12500    // 8-group node range (hist)
#define GSZ4 25000   // 4-group node range (scatter)
#define NCH 64       // edge chunks
#define CH 25000     // NE / NCH
#define HW 6250      // packed words per histogram half (2 nodes/word)
#define HSTR 12500   // words per (group,chunk) hist slice: [0,HW)=cnt, [HW,2HW)=deg

typedef __attribute__((ext_vector_type(8))) short short8;
typedef __attribute__((ext_vector_type(4))) float f32x4;
typedef __attribute__((ext_vector_type(2))) float f32x2;

// ws layout (bytes):
// dinv   [0,        400000)
// sums   [800000,   801024)
// cnt    [801024,  1201024)
// off    [1201024, 1601024)
// part   [1601024, 1603072)
// esrc   [1603072,  8003072)   src per CSR slot
// hist   [8003072, 33603072)   hist scratch (25.6 MB), then reused as xh
// Wht    [33603072,33635840)

__device__ __forceinline__ unsigned bf_rne(float f) {
    unsigned u = __float_as_uint(f);
    return (u + 0x7fffu + ((u >> 16) & 1u)) >> 16;
}
__device__ __forceinline__ unsigned pk2(float lo, float hi) {
    return bf_rne(lo) | (bf_rne(hi) << 16);
}

// ---- kernel 1: per-(chunk,group) LDS histograms, packed 16-bit, atomic-free ----
__global__ __launch_bounds__(512) void k_hist(const int* __restrict__ ei,
                                              unsigned* __restrict__ hist) {
    __shared__ unsigned loc[HSTR];  // 50 KB
    const int g = blockIdx.x & 7;
    const int t = blockIdx.x >> 3;
    const int lo = g * GSZ, hi = lo + GSZ;
    for (int j = threadIdx.x; j < HSTR; j += 512) loc[j] = 0u;
    __syncthreads();
    const int end = t * CH + CH;
    for (int i = t * CH + threadIdx.x; i < end; i += 512) {
        int r = __builtin_nontemporal_load(ei + i);
        int c = __builtin_nontemporal_load(ei + NE + i);
        if (r != c) {
            if (c >= lo && c < hi) {
                int q = c - lo;
                atomicAdd(&loc[q >> 1], 1u << ((q & 1) << 4));
            }
            if (r >= lo && r < hi) {
                int q = r - lo;
                atomicAdd(&loc[HW + (q >> 1)], 1u << ((q & 1) << 4));
            }
        }
    }
    __syncthreads();
    unsigned* dst = hist + (unsigned)(g * NCH + t) * HSTR;
    for (int j = threadIdx.x; j < HSTR; j += 512) dst[j] = loc[j];
}

// ---- kernel 2: reduce hists -> cnt, dinv; in-place per-chunk exclusive prefix --
__global__ __launch_bounds__(256) void k_reduce(unsigned* __restrict__ hist,
                                                unsigned* __restrict__ cnt,
                                                float* __restrict__ dinv) {
    int id = blockIdx.x * 256 + threadIdx.x;
    if (id >= 8 * HW) return;
    int g = id / HW;
    int w = id - g * HW;
    unsigned base = (unsigned)(g * NCH) * HSTR + w;
    unsigned run0 = 0, run1 = 0, s0 = 0, s1 = 0;
    for (int t = 0; t < NCH; ++t) {
        unsigned idx = base + (unsigned)t * HSTR;
        unsigned v = hist[idx];
        hist[idx] = run0 | (run1 << 16);  // exclusive prefix over chunks (packed)
        run0 += v & 0xffffu;
        run1 += v >> 16;
        unsigned d = hist[idx + HW];
        s0 += d & 0xffffu;
        s1 += d >> 16;
    }
    int n0 = g * GSZ + 2 * w;
    cnt[n0]     = run0;
    cnt[n0 + 1] = run1;
    dinv[n0]     = rsqrtf((float)(s0 + 1u));  // +1 self-loop
    dinv[n0 + 1] = rsqrtf((float)(s1 + 1u));
}

// ---------------- scan step 1: per-chunk sums -----------------------------------
__global__ __launch_bounds__(256) void k_scan1(const unsigned* __restrict__ cnt,
                                               unsigned* __restrict__ part) {
    __shared__ unsigned s[256];
    int i = blockIdx.x * 256 + threadIdx.x;
    unsigned v = (i < NN) ? cnt[i] : 0u;
    s[threadIdx.x] = v;
    __syncthreads();
    for (int o = 128; o > 0; o >>= 1) {
        if (threadIdx.x < o) s[threadIdx.x] += s[threadIdx.x + o];
        __syncthreads();
    }
    if (threadIdx.x == 0) part[blockIdx.x] = s[0];
}

// ------- scan step 2: exclusive scan of partials (1 block); zero BN sums --------
__global__ __launch_bounds__(512) void k_scan2(unsigned* __restrict__ part,
                                               float* __restrict__ sums) {
    __shared__ unsigned s[512];
    int t = threadIdx.x;
    if (t < 256) sums[t] = 0.f;
    unsigned v = (t < NCHUNK) ? part[t] : 0u;
    s[t] = v;
    __syncthreads();
    for (int o = 1; o < 512; o <<= 1) {
        unsigned add = (t >= o) ? s[t - o] : 0u;
        __syncthreads();
        s[t] += add;
        __syncthreads();
    }
    if (t < NCHUNK) part[t] = s[t] - v;  // exclusive
}

// ---------------- scan step 3: per-chunk exclusive offsets ----------------------
__global__ __launch_bounds__(256) void k_scan3(const unsigned* __restrict__ cnt,
                                               const unsigned* __restrict__ part,
                                               unsigned* __restrict__ off) {
    __shared__ unsigned s[256];
    int i = blockIdx.x * 256 + threadIdx.x;
    int t = threadIdx.x;
    unsigned v = (i < NN) ? cnt[i] : 0u;
    s[t] = v;
    __syncthreads();
    for (int o = 1; o < 256; o <<= 1) {
        unsigned add = (t >= o) ? s[t - o] : 0u;
        __syncthreads();
        s[t] += add;
        __syncthreads();
    }
    if (i < NN) off[i] = part[blockIdx.x] + s[t] - v;  // exclusive
}

// ---- kernel 3: 4-group scatter via packed 16-bit LDS cursors -------------------
// Group g4 covers 25000 nodes; cursors hold per-node LOCAL placement counts
// starting at this chunk's exclusive prefix (from hist); pos = off[c] + local.
// Halves can't carry: per-node totals (max in-degree ~60) << 2^16.
__global__ __launch_bounds__(512) void k_scatter(const int* __restrict__ ei,
                                                 const unsigned* __restrict__ off,
                                                 const unsigned* __restrict__ hist,
                                                 int* __restrict__ esrc) {
    __shared__ unsigned curs[GSZ4 / 2];  // 50 KB packed
    const int g = blockIdx.x & 3;
    const int t = blockIdx.x >> 2;
    const int lo = g * GSZ4, hi = lo + GSZ4;
    // init cursors from the 8-group hist prefixes (two 12500-node sub-slices)
    for (int j = threadIdx.x; j < GSZ4 / 2; j += 512) {
        int g8 = 2 * g + (j >= HW);
        int w8 = (j >= HW) ? (j - HW) : j;
        curs[j] = hist[(unsigned)(g8 * NCH + t) * HSTR + w8];
    }
    __syncthreads();
    const int end = t * CH + CH;
    for (int i = t * CH + threadIdx.x; i < end; i += 512) {
        int r = __builtin_nontemporal_load(ei + i);
        int c = __builtin_nontemporal_load(ei + NE + i);
        if (r == c || c < lo || c >= hi) continue;
        int q = c - lo;
        unsigned sh = (q & 1) << 4;
        unsigned old = atomicAdd(&curs[q >> 1], 1u << sh);  // LDS atomic
        unsigned pos = off[c] + ((old >> sh) & 0xffffu);
        esrc[pos] = r;  // L2-local slice, plain store
    }
}

// ---------------- kernel 4: x -> bf16 packed (after scatter; hist reuse) --------
__global__ void k_cvt(const float* __restrict__ x, unsigned* __restrict__ xh) {
    int i = blockIdx.x * blockDim.x + threadIdx.x;
    if (i < NN * 64) {
        f32x2 v = __builtin_nontemporal_load((const f32x2*)x + i);
        xh[i] = pk2(v.x, v.y);
    }
}

// ---------------- kernel 4b: W[k][c] -> Wht[c][k] bf16 --------------------------
__global__ void k_cvtw(const float* __restrict__ W, unsigned short* __restrict__ Wht) {
    int i = blockIdx.x * blockDim.x + threadIdx.x;  // i = k*128 + c
    if (i < D * D) {
        int k = i >> 7, c = i & 127;
        Wht[c * D + k] = (unsigned short)bf_rne(W[i]);
    }
}

// ---- kernel 5: FUSED gather + GEMM + bias + ReLU --------------------------------
// Block owns 16 output rows. Phase 1: wave w gathers rows base+4w+r (r=0..3),
// agg_c = dc*(dc*x_c + sum dr*x_r) in fp32, rounds to bf16, stages the 16x128
// A-tile in LDS (row stride 272 B: 16B-aligned, worst 8-way b128 conflict).
// Phase 2: wave w computes col-tiles {2w,2w+1} with mfma_f32_16x16x32_bf16.
// A-frag: lane l = A[row=l&15][k=(l>>4)*8+i]; B-frag = Wht[col=l&15][k];
// C/D: lane l reg j -> row=(l>>4)*4+j, col=l&15.  [layouts verified rounds 4-7]
__global__ __launch_bounds__(256) void k_gg(const unsigned* __restrict__ xh,
                                            const float* __restrict__ dinv,
                                            const unsigned* __restrict__ off,
                                            const unsigned* __restrict__ cnt,
                                            const int* __restrict__ esrc,
                                            const unsigned short* __restrict__ Wht,
                                            const float* __restrict__ b,
                                            float* __restrict__ out) {
    __shared__ unsigned lds[16 * 68];  // 16 rows x (64+4 pad) uints = 4352 B
    const int lane = threadIdx.x & 63;
    const int w = threadIdx.x >> 6;
    const int l15 = lane & 15, l4 = lane >> 4;
    const int row0 = blockIdx.x * 16;

    // ---- phase 1: gather 4 rows into LDS ----
    for (int r4 = 0; r4 < 4; ++r4) {
        const int c = row0 + w * 4 + r4;
        const float dc = dinv[c];
        unsigned xc = xh[c * 64 + lane];
        float al = dc * __uint_as_float(xc << 16);
        float ah = dc * __uint_as_float(xc & 0xffff0000u);
        const int base = off[c];
        const int n = cnt[c];
        int i = 0;
        for (; i + 4 <= n; i += 4) {
            int s0 = esrc[base + i], s1 = esrc[base + i + 1];
            int s2 = esrc[base + i + 2], s3 = esrc[base + i + 3];
            float w0 = dinv[s0], w1 = dinv[s1], w2 = dinv[s2], w3 = dinv[s3];
            unsigned p0 = xh[s0 * 64 + lane], p1 = xh[s1 * 64 + lane];
            unsigned p2 = xh[s2 * 64 + lane], p3 = xh[s3 * 64 + lane];
            al = fmaf(w0, __uint_as_float(p0 << 16), al);
            ah = fmaf(w0, __uint_as_float(p0 & 0xffff0000u), ah);
            al = fmaf(w1, __uint_as_float(p1 << 16), al);
            ah = fmaf(w1, __uint_as_float(p1 & 0xffff0000u), ah);
            al = fmaf(w2, __uint_as_float(p2 << 16), al);
            ah = fmaf(w2, __uint_as_float(p2 & 0xffff0000u), ah);
            al = fmaf(w3, __uint_as_float(p3 << 16), al);
            ah = fmaf(w3, __uint_as_float(p3 & 0xffff0000u), ah);
        }
        for (; i < n; ++i) {
            int s0 = esrc[base + i];
            float w0 = dinv[s0];
            unsigned p0 = xh[s0 * 64 + lane];
            al = fmaf(w0, __uint_as_float(p0 << 16), al);
            ah = fmaf(w0, __uint_as_float(p0 & 0xffff0000u), ah);
        }
        lds[(w * 4 + r4) * 68 + lane] = pk2(al * dc, ah * dc);
    }
    __syncthreads();

    // ---- phase 2: MFMA ----
    short8 af[4];
    #pragma unroll
    for (int kk = 0; kk < 4; ++kk)
        af[kk] = *(const short8*)((const char*)lds + l15 * 272 + kk * 64 + l4 * 16);

    #pragma unroll
    for (int n = 0; n < 2; ++n) {
        const int col = (w * 2 + n) * 16 + l15;
        short8 bf[4];
        #pragma unroll
        for (int kk = 0; kk < 4; ++kk)
            bf[kk] = *(const short8*)(Wht + col * D + kk * 32 + l4 * 8);
        f32x4 acc = (f32x4){0.f, 0.f, 0.f, 0.f};
        #pragma unroll
        for (int kk = 0; kk < 4; ++kk)
            acc = __builtin_amdgcn_mfma_f32_16x16x32_bf16(af[kk], bf[kk], acc, 0, 0, 0);
        const float bias = b[col];
        #pragma unroll
        for (int j = 0; j < 4; ++j)
            out[(row0 + l4 * 4 + j) * D + col] = fmaxf(acc[j] + bias, 0.f);
    }
}

// ------------- kernel 6: BN stats (sum, sumsq per channel) ----------------------
__global__ __launch_bounds__(256) void k_stats(const float* __restrict__ out,
                                               float* __restrict__ sums) {
    const int c  = threadIdx.x & 127;
    const int rg = threadIdx.x >> 7;
    float s = 0.f, s2 = 0.f;
    for (int row = blockIdx.x * 2 + rg; row < NN; row += gridDim.x * 2) {
        float v = out[row * D + c];
        s += v;
        s2 = fmaf(v, v, s2);
    }
    __shared__ float r1[128], r2[128];
    if (rg == 1) { r1[c] = s; r2[c] = s2; }
    __syncthreads();
    if (rg == 0) {
        s += r1[c];
        s2 += r2[c];
        unsafeAtomicAdd(&sums[c], s);
        unsafeAtomicAdd(&sums[128 + c], s2);
    }
}

// ------------- kernel 7: out = out * scale + shift  (BN affine) -----------------
__global__ __launch_bounds__(256) void k_apply(float* __restrict__ out,
                                               const float* __restrict__ gamma,
                                               const float* __restrict__ beta,
                                               const float* __restrict__ sums) {
    const float invN = 1.f / (float)NN;
    const int tid = blockIdx.x * blockDim.x + threadIdx.x;
    const int stride = gridDim.x * blockDim.x;
    const int c4 = (tid & 31) * 4;

    float4 g4 = *(const float4*)&gamma[c4];
    float4 be = *(const float4*)&beta[c4];
    float4 s4 = *(const float4*)&sums[c4];
    float4 q4 = *(const float4*)&sums[128 + c4];

    float mx = s4.x * invN, my = s4.y * invN, mz = s4.z * invN, mw = s4.w * invN;
    float scx = g4.x * rsqrtf(fmaxf(q4.x * invN - mx * mx, 0.f) + BN_EPS);
    float scy = g4.y * rsqrtf(fmaxf(q4.y * invN - my * my, 0.f) + BN_EPS);
    float scz = g4.z * rsqrtf(fmaxf(q4.z * invN - mz * mz, 0.f) + BN_EPS);
    float scw = g4.w * rsqrtf(fmaxf(q4.w * invN - mw * mw, 0.f) + BN_EPS);
    float shx = be.x - mx * scx, shy = be.y - my * scy;
    float shz = be.z - mz * scz, shw = be.w - mw * scw;

    for (int idx = tid; idx < NN * (D / 4); idx += stride) {
        float4 a = ((const float4*)out)[idx];
        a.x = a.x * scx + shx;
        a.y = a.y * scy + shy;
        a.z = a.z * scz + shz;
        a.w = a.w * scw + shw;
        ((float4*)out)[idx] = a;
    }
}

extern "C" void kernel_launch(void* const* d_in, const int* in_sizes, int n_in,
                              void* d_out, int out_size, void* d_ws, size_t ws_size,
                              hipStream_t stream) {
    const float* x     = (const float*)d_in[0];
    const int*   ei    = (const int*)d_in[1];
    const float* W     = (const float*)d_in[2];
    const float* b     = (const float*)d_in[3];
    const float* gamma = (const float*)d_in[4];
    const float* beta  = (const float*)d_in[5];
    float*       out   = (float*)d_out;

    char* ws = (char*)d_ws;
    float*          dinv = (float*)ws;
    float*          sums = (float*)(ws + 800000);
    unsigned*       cnt  = (unsigned*)(ws + 801024);
    unsigned*       off  = (unsigned*)(ws + 1201024);
    unsigned*       part = (unsigned*)(ws + 1601024);
    int*            esrc = (int*)(ws + 1603072);
    unsigned*       hist = (unsigned*)(ws + 8003072);   // 25.6 MB, reused as xh
    unsigned*       xh   = (unsigned*)(ws + 8003072);
    unsigned short* Wht  = (unsigned short*)(ws + 33603072);

    k_hist<<<NCH * 8, 512, 0, stream>>>(ei, hist);
    k_reduce<<<(8 * HW + 255) / 256, 256, 0, stream>>>(hist, cnt, dinv);
    k_scan1<<<NCHUNK, 256, 0, stream>>>(cnt, part);
    k_scan2<<<1, 512, 0, stream>>>(part, sums);
    k_scan3<<<NCHUNK, 256, 0, stream>>>(cnt, part, off);
    k_scatter<<<NCH * 4, 512, 0, stream>>>(ei, off, hist, esrc);
    k_cvt<<<25000, 256, 0, stream>>>(x, xh);
    k_cvtw<<<64, 256, 0, stream>>>(W, Wht);
    k_gg<<<NN / 16, 256, 0, stream>>>(xh, dinv, off, cnt, esrc, Wht, b, out);
    k_stats<<<512, 256, 0, stream>>>(out, sums);
    k_apply<<<2048, 256, 0, stream>>>(out, gamma, beta, sums);
}

// Round 9
// 256.519 us; speedup vs baseline: 1.1348x; 1.1348x over previous
//
#include <hip/hip_runtime.h>
#include <math.h>

#define NN 100000
#define NE 1600000
#define D 128
#define BN_EPS 1e-5f
#define NCHUNK 391   // ceil(NN/256)
#define GSZ4 25000   // 4-group node range (hist + scatter)
#define NCH 64       // edge chunks
#define CH 25000     // NE / NCH
#define HW8 6250     // words per hist half (4 nodes/word, 8-bit packed)
#define HSTR 12500   // words per (group,chunk) slice: [0,HW8)=cnt, [HW8,2*HW8)=deg

typedef __attribute__((ext_vector_type(8))) short short8;
typedef __attribute__((ext_vector_type(4))) float f32x4;
typedef __attribute__((ext_vector_type(2))) float f32x2;

// ws layout (bytes):
// dinv   [0,        400000)
// cnt    [400000,   800000)
// off    [800000,  1200000)
// part   [1200000, 1202048)
// sums8  [1202048, 1210240)   8 x 256 floats ([0..127]=s, [128..255]=s2 per slice)
// esrc   [1210368, 7610368)   src per CSR slot
// hist   [7610368, 20410368)  12.8 MB; dead after scatter, then reused as xh
// xh     [7610368, 33210368)  x in bf16 packed (written after scatter)
// Wht    [33210368,33243136)

__device__ __forceinline__ unsigned bf_rne(float f) {
    unsigned u = __float_as_uint(f);
    return (u + 0x7fffu + ((u >> 16) & 1u)) >> 16;
}
__device__ __forceinline__ unsigned pk2(float lo, float hi) {
    return bf_rne(lo) | (bf_rne(hi) << 16);
}

// ---- kernel 1: per-(chunk,group) LDS histograms, packed 8-bit, atomic-free -----
// 4 groups of 25000 nodes. Per-chunk per-node counts << 255 -> no byte carry.
__global__ __launch_bounds__(512) void k_hist(const int* __restrict__ ei,
                                              unsigned* __restrict__ hist) {
    __shared__ unsigned loc[HSTR];  // 50 KB
    const int g = blockIdx.x & 3;
    const int t = blockIdx.x >> 2;
    const int lo = g * GSZ4, hi = lo + GSZ4;
    for (int j = threadIdx.x; j < HSTR; j += 512) loc[j] = 0u;
    __syncthreads();
    const int end = t * CH + CH;
    for (int i = t * CH + threadIdx.x; i < end; i += 512) {
        int r = __builtin_nontemporal_load(ei + i);
        int c = __builtin_nontemporal_load(ei + NE + i);
        if (r != c) {
            if (c >= lo && c < hi) {
                int q = c - lo;
                atomicAdd(&loc[q >> 2], 1u << ((q & 3) << 3));
            }
            if (r >= lo && r < hi) {
                int q = r - lo;
                atomicAdd(&loc[HW8 + (q >> 2)], 1u << ((q & 3) << 3));
            }
        }
    }
    __syncthreads();
    unsigned* dst = hist + (unsigned)(g * NCH + t) * HSTR;
    for (int j = threadIdx.x; j < HSTR; j += 512) dst[j] = loc[j];
}

// ---- kernel 2: reduce hists -> cnt, dinv; in-place per-chunk exclusive prefix --
__global__ __launch_bounds__(256) void k_reduce(unsigned* __restrict__ hist,
                                                unsigned* __restrict__ cnt,
                                                float* __restrict__ dinv) {
    int id = blockIdx.x * 256 + threadIdx.x;
    if (id >= 4 * HW8) return;
    int g = id / HW8;
    int w = id - g * HW8;
    unsigned base = (unsigned)(g * NCH) * HSTR + w;
    unsigned r0 = 0, r1 = 0, r2 = 0, r3 = 0;
    unsigned s0 = 0, s1 = 0, s2 = 0, s3 = 0;
    for (int t = 0; t < NCH; ++t) {
        unsigned idx = base + (unsigned)t * HSTR;
        unsigned v = hist[idx];
        hist[idx] = r0 | (r1 << 8) | (r2 << 16) | (r3 << 24);  // exclusive prefix
        r0 += v & 255u; r1 += (v >> 8) & 255u;
        r2 += (v >> 16) & 255u; r3 += v >> 24;
        unsigned d = hist[idx + HW8];
        s0 += d & 255u; s1 += (d >> 8) & 255u;
        s2 += (d >> 16) & 255u; s3 += d >> 24;
    }
    int n0 = g * GSZ4 + 4 * w;
    cnt[n0]     = r0; cnt[n0 + 1] = r1; cnt[n0 + 2] = r2; cnt[n0 + 3] = r3;
    dinv[n0]     = rsqrtf((float)(s0 + 1u));  // +1 self-loop
    dinv[n0 + 1] = rsqrtf((float)(s1 + 1u));
    dinv[n0 + 2] = rsqrtf((float)(s2 + 1u));
    dinv[n0 + 3] = rsqrtf((float)(s3 + 1u));
}

// ---------------- scan step 1: per-chunk sums -----------------------------------
__global__ __launch_bounds__(256) void k_scan1(const unsigned* __restrict__ cnt,
                                               unsigned* __restrict__ part) {
    __shared__ unsigned s[256];
    int i = blockIdx.x * 256 + threadIdx.x;
    unsigned v = (i < NN) ? cnt[i] : 0u;
    s[threadIdx.x] = v;
    __syncthreads();
    for (int o = 128; o > 0; o >>= 1) {
        if (threadIdx.x < o) s[threadIdx.x] += s[threadIdx.x + o];
        __syncthreads();
    }
    if (threadIdx.x == 0) part[blockIdx.x] = s[0];
}

// ------- scan step 2: exclusive scan of partials (1 block); zero sums8 ----------
__global__ __launch_bounds__(512) void k_scan2(unsigned* __restrict__ part,
                                               float* __restrict__ sums8) {
    __shared__ unsigned s[512];
    int t = threadIdx.x;
    for (int j = t; j < 2048; j += 512) sums8[j] = 0.f;
    unsigned v = (t < NCHUNK) ? part[t] : 0u;
    s[t] = v;
    __syncthreads();
    for (int o = 1; o < 512; o <<= 1) {
        unsigned add = (t >= o) ? s[t - o] : 0u;
        __syncthreads();
        s[t] += add;
        __syncthreads();
    }
    if (t < NCHUNK) part[t] = s[t] - v;  // exclusive
}

// ---------------- scan step 3: per-chunk exclusive offsets ----------------------
__global__ __launch_bounds__(256) void k_scan3(const unsigned* __restrict__ cnt,
                                               const unsigned* __restrict__ part,
                                               unsigned* __restrict__ off) {
    __shared__ unsigned s[256];
    int i = blockIdx.x * 256 + threadIdx.x;
    int t = threadIdx.x;
    unsigned v = (i < NN) ? cnt[i] : 0u;
    s[t] = v;
    __syncthreads();
    for (int o = 1; o < 256; o <<= 1) {
        unsigned add = (t >= o) ? s[t - o] : 0u;
        __syncthreads();
        s[t] += add;
        __syncthreads();
    }
    if (i < NN) off[i] = part[blockIdx.x] + s[t] - v;  // exclusive
}

// ---- kernel 3: 4-group scatter via packed 16-bit LDS cursors -------------------
// Cursor word j covers nodes 2j,2j+1; init from 8-bit hist prefixes.
// local counts <= prefix(<=255) + in-chunk(<=~30) << 2^16: no half carry.
__global__ __launch_bounds__(512) void k_scatter(const int* __restrict__ ei,
                                                 const unsigned* __restrict__ off,
                                                 const unsigned* __restrict__ hist,
                                                 int* __restrict__ esrc) {
    __shared__ unsigned curs[GSZ4 / 2];  // 50 KB packed
    const int g = blockIdx.x & 3;
    const int t = blockIdx.x >> 2;
    const int lo = g * GSZ4, hi = lo + GSZ4;
    const unsigned* hb = hist + (unsigned)(g * NCH + t) * HSTR;
    for (int j = threadIdx.x; j < GSZ4 / 2; j += 512) {
        unsigned hv = hb[j >> 1];
        unsigned sh = (j & 1) << 4;  // bytes {0,1} or {2,3}
        unsigned p0 = (hv >> sh) & 255u;
        unsigned p1 = (hv >> (sh + 8)) & 255u;
        curs[j] = p0 | (p1 << 16);
    }
    __syncthreads();
    const int end = t * CH + CH;
    for (int i = t * CH + threadIdx.x; i < end; i += 512) {
        int r = __builtin_nontemporal_load(ei + i);
        int c = __builtin_nontemporal_load(ei + NE + i);
        if (r == c || c < lo || c >= hi) continue;
        int q = c - lo;
        unsigned sh = (q & 1) << 4;
        unsigned old = atomicAdd(&curs[q >> 1], 1u << sh);  // LDS atomic
        unsigned pos = off[c] + ((old >> sh) & 0xffffu);
        esrc[pos] = r;  // L2-local slice, plain store
    }
}

// ---------------- kernel 4: x -> bf16 packed (after scatter; hist reuse) --------
__global__ void k_cvt(const float* __restrict__ x, unsigned* __restrict__ xh) {
    int i = blockIdx.x * blockDim.x + threadIdx.x;
    if (i < NN * 64) {
        f32x2 v = __builtin_nontemporal_load((const f32x2*)x + i);
        xh[i] = pk2(v.x, v.y);
    }
}

// ---------------- kernel 4b: W[k][c] -> Wht[c][k] bf16 --------------------------
__global__ void k_cvtw(const float* __restrict__ W, unsigned short* __restrict__ Wht) {
    int i = blockIdx.x * blockDim.x + threadIdx.x;  // i = k*128 + c
    if (i < D * D) {
        int k = i >> 7, c = i & 127;
        Wht[c * D + k] = (unsigned short)bf_rne(W[i]);
    }
}

// -------- kernel 5: gather bf16 rows: out_c = dc*(dc*x_c + sum dr*x_r) ----------
// One wave per node (max waves in flight); 8-wide unroll for MLP.
__global__ __launch_bounds__(256) void k_gather(const unsigned* __restrict__ xh,
                                                const float* __restrict__ dinv,
                                                const unsigned* __restrict__ off,
                                                const unsigned* __restrict__ cnt,
                                                const int* __restrict__ esrc,
                                                float* __restrict__ out) {
    const int lane = threadIdx.x & 63;
    const int wave = threadIdx.x >> 6;
    const int c = blockIdx.x * 4 + wave;
    if (c >= NN) return;

    const float dc = dinv[c];
    unsigned xc = xh[c * 64 + lane];
    float al = dc * __uint_as_float(xc << 16);
    float ah = dc * __uint_as_float(xc & 0xffff0000u);

    const int base = off[c];
    const int n = cnt[c];
    int i = 0;
    for (; i + 8 <= n; i += 8) {
        int   sv[8];
        float wv[8];
        unsigned pv[8];
        #pragma unroll
        for (int j = 0; j < 8; ++j) sv[j] = esrc[base + i + j];
        #pragma unroll
        for (int j = 0; j < 8; ++j) wv[j] = dinv[sv[j]];
        #pragma unroll
        for (int j = 0; j < 8; ++j) pv[j] = xh[sv[j] * 64 + lane];
        #pragma unroll
        for (int j = 0; j < 8; ++j) {
            al = fmaf(wv[j], __uint_as_float(pv[j] << 16), al);
            ah = fmaf(wv[j], __uint_as_float(pv[j] & 0xffff0000u), ah);
        }
    }
    for (; i + 4 <= n; i += 4) {
        int s0 = esrc[base + i], s1 = esrc[base + i + 1];
        int s2 = esrc[base + i + 2], s3 = esrc[base + i + 3];
        float w0 = dinv[s0], w1 = dinv[s1], w2 = dinv[s2], w3 = dinv[s3];
        unsigned p0 = xh[s0 * 64 + lane], p1 = xh[s1 * 64 + lane];
        unsigned p2 = xh[s2 * 64 + lane], p3 = xh[s3 * 64 + lane];
        al = fmaf(w0, __uint_as_float(p0 << 16), al);
        ah = fmaf(w0, __uint_as_float(p0 & 0xffff0000u), ah);
        al = fmaf(w1, __uint_as_float(p1 << 16), al);
        ah = fmaf(w1, __uint_as_float(p1 & 0xffff0000u), ah);
        al = fmaf(w2, __uint_as_float(p2 << 16), al);
        ah = fmaf(w2, __uint_as_float(p2 & 0xffff0000u), ah);
        al = fmaf(w3, __uint_as_float(p3 << 16), al);
        ah = fmaf(w3, __uint_as_float(p3 & 0xffff0000u), ah);
    }
    for (; i < n; ++i) {
        int s0 = esrc[base + i];
        float w0 = dinv[s0];
        unsigned p0 = xh[s0 * 64 + lane];
        al = fmaf(w0, __uint_as_float(p0 << 16), al);
        ah = fmaf(w0, __uint_as_float(p0 & 0xffff0000u), ah);
    }
    al *= dc;
    ah *= dc;
    *(float2*)&out[c * D + 2 * lane] = make_float2(al, ah);
}

// ---- kernel 6: in-place MFMA GEMM + bias + ReLU + fused BN partial stats -------
// One wave owns two 16-row tiles; writes relu(out@W+b) in place, accumulates
// per-column (s, s^2) -> LDS -> one atomicAdd per col into sums8 slice blk&7.
__global__ __launch_bounds__(256, 1) void k_gemm(float* __restrict__ out,
                                                 const unsigned short* __restrict__ Wht,
                                                 const float* __restrict__ b,
                                                 float* __restrict__ sums8) {
    __shared__ float sums_lds[256];
    const int lane = threadIdx.x & 63;
    const int wv = threadIdx.x >> 6;
    const int l15 = lane & 15, l4 = lane >> 4;

    if (threadIdx.x < 256) sums_lds[threadIdx.x] = 0.f;
    __syncthreads();

    short8 bfr[8][4];
    #pragma unroll
    for (int n = 0; n < 8; ++n)
        #pragma unroll
        for (int kk = 0; kk < 4; ++kk)
            bfr[n][kk] = *(const short8*)(Wht + (n * 16 + l15) * D + kk * 32 + l4 * 8);

    float bias8[8];
    #pragma unroll
    for (int n = 0; n < 8; ++n) bias8[n] = b[n * 16 + l15];

    float sl[8], s2l[8];
    #pragma unroll
    for (int n = 0; n < 8; ++n) { sl[n] = 0.f; s2l[n] = 0.f; }

    const int gw = blockIdx.x * 4 + wv;
    #pragma unroll
    for (int t = 0; t < 2; ++t) {
        const int tile = gw * 2 + t;
        if (tile < NN / 16) {
            const int row0 = tile * 16;
            short8 af[4];
            #pragma unroll
            for (int kk = 0; kk < 4; ++kk) {
                const float* ar = out + (row0 + l15) * D + kk * 32 + l4 * 8;
                float4 a0 = *(const float4*)ar;
                float4 a1 = *(const float4*)(ar + 4);
                union { short8 s; unsigned u[4]; } cv;
                cv.u[0] = pk2(a0.x, a0.y);
                cv.u[1] = pk2(a0.z, a0.w);
                cv.u[2] = pk2(a1.x, a1.y);
                cv.u[3] = pk2(a1.z, a1.w);
                af[kk] = cv.s;
            }
            f32x4 acc[8];
            #pragma unroll
            for (int n = 0; n < 8; ++n) acc[n] = (f32x4){0.f, 0.f, 0.f, 0.f};
            #pragma unroll
            for (int n = 0; n < 8; ++n)
                #pragma unroll
                for (int kk = 0; kk < 4; ++kk)
                    acc[n] = __builtin_amdgcn_mfma_f32_16x16x32_bf16(af[kk], bfr[n][kk],
                                                                     acc[n], 0, 0, 0);
            #pragma unroll
            for (int n = 0; n < 8; ++n)
                #pragma unroll
                for (int j = 0; j < 4; ++j) {
                    int row = row0 + l4 * 4 + j;
                    float v = fmaxf(acc[n][j] + bias8[n], 0.f);
                    out[row * D + n * 16 + l15] = v;
                    sl[n] += v;
                    s2l[n] = fmaf(v, v, s2l[n]);
                }
        }
    }

    // column reduce: lanes sharing l15 across the 4 l4-groups
    #pragma unroll
    for (int n = 0; n < 8; ++n) {
        float a = sl[n], q = s2l[n];
        a += __shfl_xor(a, 16); a += __shfl_xor(a, 32);
        q += __shfl_xor(q, 16); q += __shfl_xor(q, 32);
        if (l4 == 0) {
            atomicAdd(&sums_lds[n * 16 + l15], a);
            atomicAdd(&sums_lds[128 + n * 16 + l15], q);
        }
    }
    __syncthreads();
    if (threadIdx.x < 256)
        unsafeAtomicAdd(&sums8[(blockIdx.x & 7) * 256 + threadIdx.x],
                        sums_lds[threadIdx.x]);
}

// ------------- kernel 7: out = out * scale + shift (BN affine, sums8 inline) ----
__global__ __launch_bounds__(256) void k_apply(float* __restrict__ out,
                                               const float* __restrict__ gamma,
                                               const float* __restrict__ beta,
                                               const float* __restrict__ sums8) {
    const float invN = 1.f / (float)NN;
    const int tid = blockIdx.x * blockDim.x + threadIdx.x;
    const int stride = gridDim.x * blockDim.x;
    const int c4 = (tid & 31) * 4;

    float4 s4 = make_float4(0.f, 0.f, 0.f, 0.f);
    float4 q4 = make_float4(0.f, 0.f, 0.f, 0.f);
    #pragma unroll
    for (int k = 0; k < 8; ++k) {
        float4 a = *(const float4*)&sums8[k * 256 + c4];
        float4 q = *(const float4*)&sums8[k * 256 + 128 + c4];
        s4.x += a.x; s4.y += a.y; s4.z += a.z; s4.w += a.w;
        q4.x += q.x; q4.y += q.y; q4.z += q.z; q4.w += q.w;
    }
    float4 g4 = *(const float4*)&gamma[c4];
    float4 be = *(const float4*)&beta[c4];

    float mx = s4.x * invN, my = s4.y * invN, mz = s4.z * invN, mw = s4.w * invN;
    float scx = g4.x * rsqrtf(fmaxf(q4.x * invN - mx * mx, 0.f) + BN_EPS);
    float scy = g4.y * rsqrtf(fmaxf(q4.y * invN - my * my, 0.f) + BN_EPS);
    float scz = g4.z * rsqrtf(fmaxf(q4.z * invN - mz * mz, 0.f) + BN_EPS);
    float scw = g4.w * rsqrtf(fmaxf(q4.w * invN - mw * mw, 0.f) + BN_EPS);
    float shx = be.x - mx * scx, shy = be.y - my * scy;
    float shz = be.z - mz * scz, shw = be.w - mw * scw;

    for (int idx = tid; idx < NN * (D / 4); idx += stride) {
        float4 a = ((const float4*)out)[idx];
        a.x = a.x * scx + shx;
        a.y = a.y * scy + shy;
        a.z = a.z * scz + shz;
        a.w = a.w * scw + shw;
        ((float4*)out)[idx] = a;
    }
}

extern "C" void kernel_launch(void* const* d_in, const int* in_sizes, int n_in,
                              void* d_out, int out_size, void* d_ws, size_t ws_size,
                              hipStream_t stream) {
    const float* x     = (const float*)d_in[0];
    const int*   ei    = (const int*)d_in[1];
    const float* W     = (const float*)d_in[2];
    const float* b     = (const float*)d_in[3];
    const float* gamma = (const float*)d_in[4];
    const float* beta  = (const float*)d_in[5];
    float*       out   = (float*)d_out;

    char* ws = (char*)d_ws;
    float*          dinv  = (float*)ws;
    unsigned*       cnt   = (unsigned*)(ws + 400000);
    unsigned*       off   = (unsigned*)(ws + 800000);
    unsigned*       part  = (unsigned*)(ws + 1200000);
    float*          sums8 = (float*)(ws + 1202048);
    int*            esrc  = (int*)(ws + 1210368);
    unsigned*       hist  = (unsigned*)(ws + 7610368);  // 12.8 MB
    unsigned*       xh    = (unsigned*)(ws + 7610368);  // reuse after scatter
    unsigned short* Wht   = (unsigned short*)(ws + 33210368);

    k_hist<<<NCH * 4, 512, 0, stream>>>(ei, hist);
    k_reduce<<<(4 * HW8 + 255) / 256, 256, 0, stream>>>(hist, cnt, dinv);
    k_scan1<<<NCHUNK, 256, 0, stream>>>(cnt, part);
    k_scan2<<<1, 512, 0, stream>>>(part, sums8);
    k_scan3<<<NCHUNK, 256, 0, stream>>>(cnt, part, off);
    k_scatter<<<NCH * 4, 512, 0, stream>>>(ei, off, hist, esrc);
    k_cvt<<<25000, 256, 0, stream>>>(x, xh);
    k_cvtw<<<64, 256, 0, stream>>>(W, Wht);
    k_gather<<<25000, 256, 0, stream>>>(xh, dinv, off, cnt, esrc, out);
    k_gemm<<<782, 256, 0, stream>>>(out, Wht, b, sums8);
    k_apply<<<2048, 256, 0, stream>>>(out, gamma, beta, sums8);
}